// Round 3
// baseline (279.655 us; speedup 1.0000x reference)
//
#include <hip/hip_runtime.h>

// Causal MHSA: B=2, T=2048, C=1024, H=16, Dh=64.
// Pipeline: cvt/transpose to bf16 -> QKV GEMM (MFMA, global_load_lds staging)
// -> flash attn (MFMA, max-free exp2 softmax, 64-key steps, lgkm-only fences)
// -> out GEMM -> fp32 out.
//
// R3: (a) attn steps widened 32->64 keys with exact 16-key subtile bounds
// (no wasted MFMA; only diagonal subtile masks); (b) threadfence_block
// (vmcnt(0) drain!) replaced by targeted s_waitcnt lgkmcnt(0) = 0xC07F so
// K/V global loads stay in flight across the P LDS round-trip; (c) P buffer
// row stride 72 (write conflicts 2-way=free, b128 reads bank-uniform);
// (d) both GEMMs use __builtin_amdgcn_global_load_lds width=16 (m97 ladder).

typedef __bf16 bf16;
typedef __attribute__((ext_vector_type(4))) __bf16 bf16x4;
typedef __attribute__((ext_vector_type(8))) __bf16 bf16x8;
typedef __attribute__((ext_vector_type(4))) float f32x4;

#define T_SEQ 2048
#define NHEAD 16
#define QSCALE 0.1803368801111244f  // log2(e)/sqrt(64)

__device__ __forceinline__ void async16(const bf16* g, bf16* l) {
    // 16B/lane global->LDS DMA; LDS dest = wave-uniform base + lane*16B.
    __builtin_amdgcn_global_load_lds(
        (const __attribute__((address_space(1))) void*)g,
        (__attribute__((address_space(3))) void*)l, 16, 0, 0);
}

// ---------------- conversion kernels ----------------

__global__ void cvt_f32_bf16(const float* __restrict__ in, bf16* __restrict__ out, int n) {
    int i = (blockIdx.x * blockDim.x + threadIdx.x) * 4;
    if (i < n) {
        float4 v = *(const float4*)(in + i);
        bf16x4 o;
        o.x = (bf16)v.x; o.y = (bf16)v.y; o.z = (bf16)v.z; o.w = (bf16)v.w;
        *(bf16x4*)(out + i) = o;
    }
}

// in: K_ x N_ fp32 (row-major), out: N_ x K_ bf16 (row-major)
__global__ void transpose_cvt(const float* __restrict__ in, bf16* __restrict__ out,
                              int K_, int N_) {
    __shared__ float tile[32][33];
    int k0 = blockIdx.x * 32, n0 = blockIdx.y * 32;
    int tx = threadIdx.x, ty = threadIdx.y;  // 32 x 8
    for (int r = 0; r < 32; r += 8)
        tile[ty + r][tx] = in[(k0 + ty + r) * N_ + n0 + tx];
    __syncthreads();
    for (int r = 0; r < 32; r += 8)
        out[(n0 + ty + r) * K_ + k0 + tx] = (bf16)tile[tx][ty + r];
}

// ---------------- GEMM 1: qkv = x @ qkv_w + b, scatter to Q/K/Vt ----------------
// 128x128 tile, BK=32, 4 waves 2x2, 4x4 16x16x32 MFMAs per wave.
// Staging: thread t <-> As elements 8t..8t+7 (contiguous) => global_load_lds.

__global__ __launch_bounds__(256) void gemm_qkv(
    const bf16* __restrict__ A, const bf16* __restrict__ Bt,
    const float* __restrict__ bias,
    bf16* __restrict__ Qo, bf16* __restrict__ Ko, bf16* __restrict__ Vt) {
    __shared__ __align__(16) bf16 As[128 * 32];
    __shared__ __align__(16) bf16 Bs[128 * 32];
    const int t = threadIdx.x;
    const int lane = t & 63, wave = t >> 6;
    const int l15 = lane & 15, quad = lane >> 4;
    const int wm = wave & 1, wn = wave >> 1;
    const int m0 = blockIdx.y * 128, n0 = blockIdx.x * 128;

    f32x4 acc[4][4] = {};

    const bf16* ag = A + (m0 + (t >> 2)) * 1024 + (t & 3) * 8;
    const bf16* bg = Bt + (n0 + (t >> 2)) * 1024 + (t & 3) * 8;
    bf16* as0 = As + wave * 512;
    bf16* as1 = As + 2048 + wave * 512;
    bf16* bs0 = Bs + wave * 512;
    bf16* bs1 = Bs + 2048 + wave * 512;

    for (int k0 = 0; k0 < 1024; k0 += 32) {
        async16(ag + k0, as0);
        async16(ag + 64 * 1024 + k0, as1);
        async16(bg + k0, bs0);
        async16(bg + 64 * 1024 + k0, bs1);
        __syncthreads();  // drains vmcnt -> staged tiles visible
        bf16x8 af[4], bfr[4];
        for (int i = 0; i < 4; i++)
            af[i] = *(const bf16x8*)(As + (wm * 64 + i * 16 + l15) * 32 + quad * 8);
        for (int j = 0; j < 4; j++)
            bfr[j] = *(const bf16x8*)(Bs + (wn * 64 + j * 16 + l15) * 32 + quad * 8);
        for (int i = 0; i < 4; i++)
            for (int j = 0; j < 4; j++)
                acc[i][j] = __builtin_amdgcn_mfma_f32_16x16x32_bf16(af[i], bfr[j], acc[i][j], 0, 0, 0);
        __syncthreads();
    }

    // epilogue: col -> (sec,h,d); row -> (b,t)
    for (int i = 0; i < 4; i++) {
        for (int j = 0; j < 4; j++) {
            int col = n0 + wn * 64 + j * 16 + l15;
            float bv = bias[col];
            int sec = col >> 10, c2 = col & 1023, h = c2 >> 6, d = c2 & 63;
            for (int r = 0; r < 4; r++) {
                int row = m0 + wm * 64 + i * 16 + quad * 4 + r;
                int b = row >> 11, tt = row & 2047;
                int bh = b * NHEAD + h;
                float v = acc[i][j][r] + bv;
                if (sec == 0)
                    Qo[(bh * T_SEQ + tt) * 64 + d] = (bf16)(v * QSCALE);
                else if (sec == 1)
                    Ko[(bh * T_SEQ + tt) * 64 + d] = (bf16)v;
                else
                    Vt[(bh * 64 + d) * T_SEQ + tt] = (bf16)v;
            }
        }
    }
}

// ---------------- attention ----------------
// Block = 4 waves: tiles {p, 127-p} of one (b,h), 2 waves/tile split by
// 64-key-group parity (max-free exp2 softmax => partials sum). Per group:
// up to 4 exact 16-key subtiles (count = qt+1 total), only diagonal masks.
#define PSTRIDE 72  // P row stride (elems): pads 64 -> bank-friendly
__global__ __launch_bounds__(256, 4) void attn(
    const bf16* __restrict__ Q, const bf16* __restrict__ K,
    const bf16* __restrict__ Vt, bf16* __restrict__ AO) {
    __shared__ __align__(16) bf16 Pb[4][16 * PSTRIDE];
    __shared__ float accb[2][16][64];
    __shared__ float lb[2][16];
    const int lane = threadIdx.x & 63, wave = threadIdx.x >> 6;
    const int l15 = lane & 15, quad = lane >> 4;
    const int tile = wave >> 1;   // 0 -> tile p, 1 -> tile 127-p
    const int ph = wave & 1;      // 64-key-group parity this wave handles
    const int bh = blockIdx.y;
    const int pair = blockIdx.x;  // 0..63
    const int qt = tile ? (127 - pair) : pair;
    const int t0 = qt * 16;

    const bf16* qp = Q + (bh * T_SEQ + t0) * 64;
    const bf16* kp = K + bh * T_SEQ * 64;
    const bf16* vp = Vt + bh * 64 * T_SEQ;
    bf16* pw = &Pb[wave][0];

    bf16x8 qf0 = *(const bf16x8*)(qp + l15 * 64 + quad * 8);
    bf16x8 qf1 = *(const bf16x8*)(qp + l15 * 64 + 32 + quad * 8);

    f32x4 acc[4] = {};
    float lsum[4] = {0.f, 0.f, 0.f, 0.f};

    const int nsub = qt + 1;           // exact 16-key subtiles (keys 0..t0+15)
    const int ngrp = (nsub + 3) >> 2;  // 64-key groups
    for (int g = ph; g < ngrp; g += 2) {
        const int kb0 = g * 64;
        const int na = min(4, nsub - 4 * g);                  // active subtiles
        const int ndiag = (g == ngrp - 1) ? (na - 1) : 99;    // diagonal subtile
        f32x4 sc[4];
        for (int n = 0; n < 4; n++) {
            if (n < na) {
                const bf16* kbase = kp + (kb0 + n * 16 + l15) * 64 + quad * 8;
                bf16x8 kf0 = *(const bf16x8*)kbase;
                bf16x8 kf1 = *(const bf16x8*)(kbase + 32);
                f32x4 z = {};
                z = __builtin_amdgcn_mfma_f32_16x16x32_bf16(qf0, kf0, z, 0, 0, 0);
                z = __builtin_amdgcn_mfma_f32_16x16x32_bf16(qf1, kf1, z, 0, 0, 0);
                sc[n] = z;
            }
        }
        for (int n = 0; n < 4; n++) {
            for (int r = 0; r < 4; r++) {
                float e = 0.0f;
                if (n < na) {
                    float v = sc[n][r];
                    if (n == ndiag) {
                        int key = kb0 + n * 16 + l15;
                        int qrow = t0 + quad * 4 + r;
                        if (key > qrow) v = -100000.0f;
                    }
                    e = __builtin_amdgcn_exp2f(v);
                }
                bf16 eb = (bf16)e;
                lsum[r] += (float)e;  // e already bf16-roundable; use fp32 e
                pw[(quad * 4 + r) * PSTRIDE + n * 16 + l15] = eb;
            }
        }
        // lgkmcnt(0) ONLY (0xC07F): P writes land before A-frag reads,
        // without draining the global-load queue (vmcnt untouched).
        __builtin_amdgcn_s_waitcnt(0xC07F);
        bf16x8 pf0 = *(const bf16x8*)(pw + l15 * PSTRIDE + quad * 8);
        bf16x8 pf1 = *(const bf16x8*)(pw + l15 * PSTRIDE + 32 + quad * 8);
        for (int j = 0; j < 4; j++) {
            const bf16* vbase = vp + (j * 16 + l15) * T_SEQ + kb0 + quad * 8;
            bf16x8 vf0 = *(const bf16x8*)vbase;
            bf16x8 vf1 = *(const bf16x8*)(vbase + 32);
            acc[j] = __builtin_amdgcn_mfma_f32_16x16x32_bf16(pf0, vf0, acc[j], 0, 0, 0);
            acc[j] = __builtin_amdgcn_mfma_f32_16x16x32_bf16(pf1, vf1, acc[j], 0, 0, 0);
        }
        __builtin_amdgcn_s_waitcnt(0xC07F);  // pf reads done before next writes
    }

    // lsum was accumulated in fp32 of exp2 while P stores bf16-rounded values;
    // the bf16 rounding of P is zero-mean, and l is a 16-term+ sum: keep fp32.
    float lred[4];
    for (int r = 0; r < 4; r++) {
        float v = lsum[r];
        v += __shfl_xor(v, 1, 16);
        v += __shfl_xor(v, 2, 16);
        v += __shfl_xor(v, 4, 16);
        v += __shfl_xor(v, 8, 16);
        lred[r] = v;
    }

    // merge parity partials (pure addition: max-free softmax)
    if (ph == 1) {
        for (int j = 0; j < 4; j++)
            for (int r = 0; r < 4; r++)
                accb[tile][quad * 4 + r][j * 16 + l15] = acc[j][r];
        if (l15 == 0)
            for (int r = 0; r < 4; r++)
                lb[tile][quad * 4 + r] = lred[r];
    }
    __syncthreads();
    if (ph == 0) {
        const int b = bh >> 4, h = bh & 15;
        bf16* aop = AO + (b * T_SEQ + t0) * 1024 + h * 64;
        for (int r = 0; r < 4; r++) {
            float linv = 1.0f / (lred[r] + lb[tile][quad * 4 + r]);
            for (int j = 0; j < 4; j++) {
                float o = acc[j][r] + accb[tile][quad * 4 + r][j * 16 + l15];
                aop[(quad * 4 + r) * 1024 + j * 16 + l15] = (bf16)(o * linv);
            }
        }
    }
}

// ---------------- GEMM 2: out = AO @ out_w + out_b (fp32 out) ----------------
__global__ __launch_bounds__(256) void gemm_out_k(
    const bf16* __restrict__ A, const bf16* __restrict__ Bt,
    const float* __restrict__ bias, float* __restrict__ out) {
    __shared__ __align__(16) bf16 As[128 * 32];
    __shared__ __align__(16) bf16 Bs[128 * 32];
    const int t = threadIdx.x;
    const int lane = t & 63, wave = t >> 6;
    const int l15 = lane & 15, quad = lane >> 4;
    const int wm = wave & 1, wn = wave >> 1;
    const int m0 = blockIdx.y * 128, n0 = blockIdx.x * 128;

    f32x4 acc[4][4] = {};

    const bf16* ag = A + (m0 + (t >> 2)) * 1024 + (t & 3) * 8;
    const bf16* bg = Bt + (n0 + (t >> 2)) * 1024 + (t & 3) * 8;
    bf16* as0 = As + wave * 512;
    bf16* as1 = As + 2048 + wave * 512;
    bf16* bs0 = Bs + wave * 512;
    bf16* bs1 = Bs + 2048 + wave * 512;

    for (int k0 = 0; k0 < 1024; k0 += 32) {
        async16(ag + k0, as0);
        async16(ag + 64 * 1024 + k0, as1);
        async16(bg + k0, bs0);
        async16(bg + 64 * 1024 + k0, bs1);
        __syncthreads();
        bf16x8 af[4], bfr[4];
        for (int i = 0; i < 4; i++)
            af[i] = *(const bf16x8*)(As + (wm * 64 + i * 16 + l15) * 32 + quad * 8);
        for (int j = 0; j < 4; j++)
            bfr[j] = *(const bf16x8*)(Bs + (wn * 64 + j * 16 + l15) * 32 + quad * 8);
        for (int i = 0; i < 4; i++)
            for (int j = 0; j < 4; j++)
                acc[i][j] = __builtin_amdgcn_mfma_f32_16x16x32_bf16(af[i], bfr[j], acc[i][j], 0, 0, 0);
        __syncthreads();
    }

    for (int i = 0; i < 4; i++) {
        for (int j = 0; j < 4; j++) {
            int col = n0 + wn * 64 + j * 16 + l15;
            float bv = bias[col];
            for (int r = 0; r < 4; r++) {
                int row = m0 + wm * 64 + i * 16 + quad * 4 + r;
                out[row * 1024 + col] = acc[i][j][r] + bv;
            }
        }
    }
}

// ---------------- launch ----------------
extern "C" void kernel_launch(void* const* d_in, const int* in_sizes, int n_in,
                              void* d_out, int out_size, void* d_ws, size_t ws_size,
                              hipStream_t stream) {
    const float* x     = (const float*)d_in[0];  // (2,2048,1024)
    const float* qkv_w = (const float*)d_in[1];  // (1024,3072)
    const float* qkv_b = (const float*)d_in[2];  // (3072,)
    const float* out_w = (const float*)d_in[3];  // (1024,1024)
    const float* out_b = (const float*)d_in[4];  // (1024,)
    float* out = (float*)d_out;

    char* ws = (char*)d_ws;
    bf16* xb   = (bf16*)(ws);                     // 8 MB
    bf16* wbT  = (bf16*)(ws + (8ull << 20));      // 6 MB  (3072 x 1024)
    bf16* owbT = (bf16*)(ws + (14ull << 20));     // 2 MB  (1024 x 1024)
    bf16* Qb   = (bf16*)(ws + (16ull << 20));     // 8 MB  (B,H,T,Dh), pre-scaled
    bf16* Kb   = (bf16*)(ws + (24ull << 20));     // 8 MB  (B,H,T,Dh)
    bf16* Vt   = (bf16*)(ws + (32ull << 20));     // 8 MB  (B,H,Dh,T)
    bf16* AO   = (bf16*)(ws + (40ull << 20));     // 8 MB  (B,T,C)

    cvt_f32_bf16<<<4096, 256, 0, stream>>>(x, xb, 2 * 2048 * 1024);
    transpose_cvt<<<dim3(32, 96), dim3(32, 8), 0, stream>>>(qkv_w, wbT, 1024, 3072);
    transpose_cvt<<<dim3(32, 32), dim3(32, 8), 0, stream>>>(out_w, owbT, 1024, 1024);
    gemm_qkv<<<dim3(24, 32), 256, 0, stream>>>(xb, wbT, qkv_b, Qb, Kb, Vt);
    attn<<<dim3(64, 32), 256, 0, stream>>>(Qb, Kb, Vt, AO);
    gemm_out_k<<<dim3(8, 32), 256, 0, stream>>>(AO, owbT, out_b, out);
}

// Round 4
// 203.431 us; speedup vs baseline: 1.3747x; 1.3747x over previous
//
#include <hip/hip_runtime.h>

// Causal MHSA: B=2, T=2048, C=1024, H=16, Dh=64.
// cvt/transpose -> QKV GEMM (MFMA, global_load_lds) -> flash attn -> out GEMM.
//
// R4 attn: L3-BW roofline fix. Block = 4 waves x 16 Q-rows (64 rows), K/V
// staged per 64-key chunk into LDS (double-buffered, prefetch after barrier),
// shared by all 4 waves (traffic /4). bh grouped per XCD (lin&7) so each
// XCD's K/V working set (4 bh x 512 KB = 2 MB) fits its 4 MB L2. K/V LDS
// layout XOR-swizzled via the GLOBAL address (LDS side must stay lane-
// contiguous for global_load_lds): granule p = g ^ (key&7) -> b128 fragment
// reads are 2-way (free) instead of 16-way same-bank. R interleaved
// big/small in dispatch order to flatten per-CU work.

typedef __bf16 bf16;
typedef __attribute__((ext_vector_type(4))) __bf16 bf16x4;
typedef __attribute__((ext_vector_type(8))) __bf16 bf16x8;
typedef __attribute__((ext_vector_type(4))) float f32x4;

#define T_SEQ 2048
#define NHEAD 16
#define QSCALE 0.1803368801111244f  // log2(e)/sqrt(64)

__device__ __forceinline__ void async16(const bf16* g, const bf16* l) {
    // 16B/lane global->LDS DMA; LDS dest = wave-uniform base + lane*16B.
    __builtin_amdgcn_global_load_lds(
        (const __attribute__((address_space(1))) void*)g,
        (__attribute__((address_space(3))) void*)l, 16, 0, 0);
}

// ---------------- conversion kernels ----------------

__global__ void cvt_f32_bf16(const float* __restrict__ in, bf16* __restrict__ out, int n) {
    int i = (blockIdx.x * blockDim.x + threadIdx.x) * 4;
    if (i < n) {
        float4 v = *(const float4*)(in + i);
        bf16x4 o;
        o.x = (bf16)v.x; o.y = (bf16)v.y; o.z = (bf16)v.z; o.w = (bf16)v.w;
        *(bf16x4*)(out + i) = o;
    }
}

__global__ void transpose_cvt(const float* __restrict__ in, bf16* __restrict__ out,
                              int K_, int N_) {
    __shared__ float tile[32][33];
    int k0 = blockIdx.x * 32, n0 = blockIdx.y * 32;
    int tx = threadIdx.x, ty = threadIdx.y;  // 32 x 8
    for (int r = 0; r < 32; r += 8)
        tile[ty + r][tx] = in[(k0 + ty + r) * N_ + n0 + tx];
    __syncthreads();
    for (int r = 0; r < 32; r += 8)
        out[(n0 + ty + r) * K_ + k0 + tx] = (bf16)tile[tx][ty + r];
}

// ---------------- GEMM 1: qkv = x @ qkv_w + b, scatter to Q/K/Vt ----------------

__global__ __launch_bounds__(256) void gemm_qkv(
    const bf16* __restrict__ A, const bf16* __restrict__ Bt,
    const float* __restrict__ bias,
    bf16* __restrict__ Qo, bf16* __restrict__ Ko, bf16* __restrict__ Vt) {
    __shared__ __align__(16) bf16 As[128 * 32];
    __shared__ __align__(16) bf16 Bs[128 * 32];
    const int t = threadIdx.x;
    const int lane = t & 63, wave = t >> 6;
    const int l15 = lane & 15, quad = lane >> 4;
    const int wm = wave & 1, wn = wave >> 1;
    const int m0 = blockIdx.y * 128, n0 = blockIdx.x * 128;

    f32x4 acc[4][4] = {};

    const bf16* ag = A + (m0 + (t >> 2)) * 1024 + (t & 3) * 8;
    const bf16* bg = Bt + (n0 + (t >> 2)) * 1024 + (t & 3) * 8;
    bf16* as0 = As + wave * 512;
    bf16* as1 = As + 2048 + wave * 512;
    bf16* bs0 = Bs + wave * 512;
    bf16* bs1 = Bs + 2048 + wave * 512;

    for (int k0 = 0; k0 < 1024; k0 += 32) {
        async16(ag + k0, as0);
        async16(ag + 64 * 1024 + k0, as1);
        async16(bg + k0, bs0);
        async16(bg + 64 * 1024 + k0, bs1);
        __syncthreads();
        bf16x8 af[4], bfr[4];
        for (int i = 0; i < 4; i++)
            af[i] = *(const bf16x8*)(As + (wm * 64 + i * 16 + l15) * 32 + quad * 8);
        for (int j = 0; j < 4; j++)
            bfr[j] = *(const bf16x8*)(Bs + (wn * 64 + j * 16 + l15) * 32 + quad * 8);
        for (int i = 0; i < 4; i++)
            for (int j = 0; j < 4; j++)
                acc[i][j] = __builtin_amdgcn_mfma_f32_16x16x32_bf16(af[i], bfr[j], acc[i][j], 0, 0, 0);
        __syncthreads();
    }

    for (int i = 0; i < 4; i++) {
        for (int j = 0; j < 4; j++) {
            int col = n0 + wn * 64 + j * 16 + l15;
            float bv = bias[col];
            int sec = col >> 10, c2 = col & 1023, h = c2 >> 6, d = c2 & 63;
            for (int r = 0; r < 4; r++) {
                int row = m0 + wm * 64 + i * 16 + quad * 4 + r;
                int b = row >> 11, tt = row & 2047;
                int bh = b * NHEAD + h;
                float v = acc[i][j][r] + bv;
                if (sec == 0)
                    Qo[(bh * T_SEQ + tt) * 64 + d] = (bf16)(v * QSCALE);
                else if (sec == 1)
                    Ko[(bh * T_SEQ + tt) * 64 + d] = (bf16)v;
                else
                    Vt[(bh * 64 + d) * T_SEQ + tt] = (bf16)v;
            }
        }
    }
}

// ---------------- attention ----------------
// 1024 blocks x 256 thr. Block: 64 Q-rows (4 waves x 16) of one (b,h),
// iterating 64-key LDS chunks. lin&7 selects XCD-group of 4 bh.
#define PSTR 64
__global__ __launch_bounds__(256, 4) void attn(
    const bf16* __restrict__ Q, const bf16* __restrict__ K,
    const bf16* __restrict__ Vt, bf16* __restrict__ AO) {
    __shared__ __align__(16) bf16 Ks[2][64 * 64];
    __shared__ __align__(16) bf16 Vs[2][64 * 64];
    __shared__ __align__(16) bf16 Pb[4][16 * PSTR];
    const int lane = threadIdx.x & 63, wave = threadIdx.x >> 6;
    const int l15 = lane & 15, quad = lane >> 4;
    const int lin = blockIdx.x;
    const int s = lin >> 3;
    const int bh = ((lin & 7) << 2) | (s & 3);  // 4 bh per XCD residue class
    const int k5 = s >> 2;                      // 0..31
    const int R = (k5 & 1) ? (k5 >> 1) : (31 - (k5 >> 1));  // big/small interleave
    const int Rb = R * 64;

    const bf16* qp = Q + (bh * T_SEQ + Rb + wave * 16) * 64;
    const bf16* kp = K + bh * T_SEQ * 64;
    const bf16* vp = Vt + bh * 64 * T_SEQ;
    bf16* pw = &Pb[wave][0];

    bf16x8 qf0 = *(const bf16x8*)(qp + l15 * 64 + quad * 8);
    bf16x8 qf1 = *(const bf16x8*)(qp + l15 * 64 + 32 + quad * 8);

    f32x4 acc[4] = {};
    float lsum[4] = {0.f, 0.f, 0.f, 0.f};

    // XOR swizzle: logical granule g (16B) of row x lives at physical
    // granule g ^ (x&7). Applied on the global side during staging.
    const int sx = (quad ^ (l15 & 7)) << 3;  // frag-read swizzled elem offset

    // stage chunk (keys kb..kb+63) into buffer b
    auto stage = [&](int kb, int b) {
        const bf16* kg = kp + kb * 64;
        for (int i = 0; i < 2; i++) {
            int G = (wave * 2 + i) * 64 + lane;  // physical granule in chunk
            int key = G >> 3, p = G & 7;
            async16(kg + key * 64 + ((p ^ (key & 7)) << 3), &Ks[b][(wave * 2 + i) * 512]);
        }
        for (int i = 0; i < 2; i++) {
            int d = (wave * 2 + i) * 8 + (lane >> 3);
            async16(vp + d * T_SEQ + kb + (((lane & 7) ^ (d & 7)) << 3),
                    &Vs[b][(wave * 2 + i) * 512]);
        }
    };

    stage(0, 0);
    for (int c = 0; c <= R; c++) {
        __syncthreads();  // drains stage(c); all waves aligned
        if (c < R) stage((c + 1) * 64, (c + 1) & 1);
        const bf16* ksb = &Ks[c & 1][0];
        const bf16* vsb = &Vs[c & 1][0];
        const bool dg = (c == R);
        const int na = dg ? (wave + 1) : 4;
        const int kb = c * 64;

        f32x4 sc[4];
        for (int n = 0; n < 4; n++) {
            if (n < na) {
                const bf16* kbase = ksb + (n * 16 + l15) * 64;
                bf16x8 kf0 = *(const bf16x8*)(kbase + sx);
                bf16x8 kf1 = *(const bf16x8*)(kbase + (sx ^ 32));
                f32x4 z = {};
                z = __builtin_amdgcn_mfma_f32_16x16x32_bf16(qf0, kf0, z, 0, 0, 0);
                z = __builtin_amdgcn_mfma_f32_16x16x32_bf16(qf1, kf1, z, 0, 0, 0);
                sc[n] = z;
            }
        }
        for (int n = 0; n < 4; n++) {
            for (int r = 0; r < 4; r++) {
                float e = 0.0f;
                if (n < na) {
                    float v = sc[n][r];
                    if (dg && n == na - 1) {  // diagonal subtile of this wave
                        int key = kb + n * 16 + l15;
                        int qrow = Rb + wave * 16 + quad * 4 + r;
                        if (key > qrow) v = -100000.0f;
                    }
                    e = __builtin_amdgcn_exp2f(v);
                }
                lsum[r] += e;
                pw[(quad * 4 + r) * PSTR + n * 16 + l15] = (bf16)e;
            }
        }
        // lgkmcnt(0) only (0xC07F): P round-trip ordering w/o draining vmcnt
        // (the in-flight stage(c+1) keeps streaming).
        __builtin_amdgcn_s_waitcnt(0xC07F);
        bf16x8 pf0 = *(const bf16x8*)(pw + l15 * PSTR + quad * 8);
        bf16x8 pf1 = *(const bf16x8*)(pw + l15 * PSTR + 32 + quad * 8);
        for (int j = 0; j < 4; j++) {
            const bf16* vbase = vsb + (j * 16 + l15) * 64;
            bf16x8 vf0 = *(const bf16x8*)(vbase + sx);
            bf16x8 vf1 = *(const bf16x8*)(vbase + (sx ^ 32));
            acc[j] = __builtin_amdgcn_mfma_f32_16x16x32_bf16(pf0, vf0, acc[j], 0, 0, 0);
            acc[j] = __builtin_amdgcn_mfma_f32_16x16x32_bf16(pf1, vf1, acc[j], 0, 0, 0);
        }
        // next P write happens after the next barrier; no trailing wait needed
    }

    float linv[4];
    for (int r = 0; r < 4; r++) {
        float v = lsum[r];
        v += __shfl_xor(v, 1, 16);
        v += __shfl_xor(v, 2, 16);
        v += __shfl_xor(v, 4, 16);
        v += __shfl_xor(v, 8, 16);
        linv[r] = 1.0f / v;
    }
    const int b = bh >> 4, h = bh & 15;
    bf16* aop = AO + (b * T_SEQ + Rb + wave * 16) * 1024 + h * 64;
    for (int r = 0; r < 4; r++)
        for (int j = 0; j < 4; j++)
            aop[(quad * 4 + r) * 1024 + j * 16 + l15] = (bf16)(acc[j][r] * linv[r]);
}

// ---------------- GEMM 2: out = AO @ out_w + out_b (fp32 out) ----------------
__global__ __launch_bounds__(256) void gemm_out_k(
    const bf16* __restrict__ A, const bf16* __restrict__ Bt,
    const float* __restrict__ bias, float* __restrict__ out) {
    __shared__ __align__(16) bf16 As[128 * 32];
    __shared__ __align__(16) bf16 Bs[128 * 32];
    const int t = threadIdx.x;
    const int lane = t & 63, wave = t >> 6;
    const int l15 = lane & 15, quad = lane >> 4;
    const int wm = wave & 1, wn = wave >> 1;
    const int m0 = blockIdx.y * 128, n0 = blockIdx.x * 128;

    f32x4 acc[4][4] = {};

    const bf16* ag = A + (m0 + (t >> 2)) * 1024 + (t & 3) * 8;
    const bf16* bg = Bt + (n0 + (t >> 2)) * 1024 + (t & 3) * 8;
    bf16* as0 = As + wave * 512;
    bf16* as1 = As + 2048 + wave * 512;
    bf16* bs0 = Bs + wave * 512;
    bf16* bs1 = Bs + 2048 + wave * 512;

    for (int k0 = 0; k0 < 1024; k0 += 32) {
        async16(ag + k0, as0);
        async16(ag + 64 * 1024 + k0, as1);
        async16(bg + k0, bs0);
        async16(bg + 64 * 1024 + k0, bs1);
        __syncthreads();
        bf16x8 af[4], bfr[4];
        for (int i = 0; i < 4; i++)
            af[i] = *(const bf16x8*)(As + (wm * 64 + i * 16 + l15) * 32 + quad * 8);
        for (int j = 0; j < 4; j++)
            bfr[j] = *(const bf16x8*)(Bs + (wn * 64 + j * 16 + l15) * 32 + quad * 8);
        for (int i = 0; i < 4; i++)
            for (int j = 0; j < 4; j++)
                acc[i][j] = __builtin_amdgcn_mfma_f32_16x16x32_bf16(af[i], bfr[j], acc[i][j], 0, 0, 0);
        __syncthreads();
    }

    for (int i = 0; i < 4; i++) {
        for (int j = 0; j < 4; j++) {
            int col = n0 + wn * 64 + j * 16 + l15;
            float bv = bias[col];
            for (int r = 0; r < 4; r++) {
                int row = m0 + wm * 64 + i * 16 + quad * 4 + r;
                out[row * 1024 + col] = acc[i][j][r] + bv;
            }
        }
    }
}

// ---------------- launch ----------------
extern "C" void kernel_launch(void* const* d_in, const int* in_sizes, int n_in,
                              void* d_out, int out_size, void* d_ws, size_t ws_size,
                              hipStream_t stream) {
    const float* x     = (const float*)d_in[0];
    const float* qkv_w = (const float*)d_in[1];
    const float* qkv_b = (const float*)d_in[2];
    const float* out_w = (const float*)d_in[3];
    const float* out_b = (const float*)d_in[4];
    float* out = (float*)d_out;

    char* ws = (char*)d_ws;
    bf16* xb   = (bf16*)(ws);                     // 8 MB
    bf16* wbT  = (bf16*)(ws + (8ull << 20));      // 6 MB  (3072 x 1024)
    bf16* owbT = (bf16*)(ws + (14ull << 20));     // 2 MB  (1024 x 1024)
    bf16* Qb   = (bf16*)(ws + (16ull << 20));     // 8 MB  (B,H,T,Dh), pre-scaled
    bf16* Kb   = (bf16*)(ws + (24ull << 20));     // 8 MB  (B,H,T,Dh)
    bf16* Vt   = (bf16*)(ws + (32ull << 20));     // 8 MB  (B,H,Dh,T)
    bf16* AO   = (bf16*)(ws + (40ull << 20));     // 8 MB  (B,T,C)

    cvt_f32_bf16<<<4096, 256, 0, stream>>>(x, xb, 2 * 2048 * 1024);
    transpose_cvt<<<dim3(32, 96), dim3(32, 8), 0, stream>>>(qkv_w, wbT, 1024, 3072);
    transpose_cvt<<<dim3(32, 32), dim3(32, 8), 0, stream>>>(out_w, owbT, 1024, 1024);
    gemm_qkv<<<dim3(24, 32), 256, 0, stream>>>(xb, wbT, qkv_b, Qb, Kb, Vt);
    attn<<<1024, 256, 0, stream>>>(Qb, Kb, Vt, AO);
    gemm_out_k<<<dim3(8, 32), 256, 0, stream>>>(AO, owbT, out_b, out);
}

// Round 6
// 202.434 us; speedup vs baseline: 1.3815x; 1.0049x over previous
//
#include <hip/hip_runtime.h>

// Causal MHSA: B=2, T=2048, C=1024, H=16, Dh=64.
// prep (cvt+transposes, fused) -> QKV GEMM (MFMA, global_load_lds) ->
// flash attn (MFMA, max-free exp2 softmax) -> out GEMM -> fp32 out.
//
// R6 = R5 with the staging-unit bugfix: stage() takes kb in KEY units;
// call sites must pass (c+1)*64, not c+1. (R5 staged keys c..c+63 per chunk.)
//
// attn structure (R5): 256 blocks x 512 thr (8 waves x 16 Q-rows = 128-row
// tile). Block handles tile pair {15-pr, pr} of one bh sequentially = exactly
// 34 chunk-stages per block (uniform by construction). K/V staged per 64-key
// chunk (double-buffered, 1 async16/thread/operand), shared by 8 waves.
// XCD-local bh via blockIdx&7 (4 bh per XCD -> 2 MB K/V fits 4 MB L2).
// XOR-swizzled K/V LDS layout, swizzle applied on the GLOBAL address side
// (LDS side must stay lane-contiguous for global_load_lds).

typedef __bf16 bf16;
typedef __attribute__((ext_vector_type(4))) __bf16 bf16x4;
typedef __attribute__((ext_vector_type(8))) __bf16 bf16x8;
typedef __attribute__((ext_vector_type(4))) float f32x4;

#define T_SEQ 2048
#define NHEAD 16
#define QSCALE 0.1803368801111244f  // log2(e)/sqrt(64)

__device__ __forceinline__ void async16(const bf16* g, const bf16* l) {
    __builtin_amdgcn_global_load_lds(
        (const __attribute__((address_space(1))) void*)g,
        (__attribute__((address_space(3))) void*)l, 16, 0, 0);
}

// ---------------- fused prep: cvt x -> bf16; transpose+cvt both weights ----
// blocks [0,4096): cvt x; [4096,7168): qkv_w^T; [7168,8192): out_w^T.
__global__ __launch_bounds__(256) void prep(
    const float* __restrict__ x, bf16* __restrict__ xb,
    const float* __restrict__ qkv_w, bf16* __restrict__ wbT,
    const float* __restrict__ out_w, bf16* __restrict__ owbT) {
    const int bid = blockIdx.x, tid = threadIdx.x;
    if (bid < 4096) {
        int i = (bid * 256 + tid) * 4;
        float4 v = *(const float4*)(x + i);
        bf16x4 o;
        o.x = (bf16)v.x; o.y = (bf16)v.y; o.z = (bf16)v.z; o.w = (bf16)v.w;
        *(bf16x4*)(xb + i) = o;
        return;
    }
    __shared__ float tile[32][33];
    const float* in;
    bf16* out;
    int K_, N_, b;
    if (bid < 7168) { b = bid - 4096; in = qkv_w; out = wbT; K_ = 1024; N_ = 3072; }
    else            { b = bid - 7168; in = out_w; out = owbT; K_ = 1024; N_ = 1024; }
    int k0 = (b & 31) * 32, n0 = (b >> 5) * 32;
    int tx = tid & 31, ty = tid >> 5;  // 32 x 8
    for (int r = 0; r < 32; r += 8)
        tile[ty + r][tx] = in[(k0 + ty + r) * N_ + n0 + tx];
    __syncthreads();
    for (int r = 0; r < 32; r += 8)
        out[(n0 + ty + r) * K_ + k0 + tx] = (bf16)tile[tx][ty + r];
}

// ---------------- GEMM 1: qkv = x @ qkv_w + b, scatter to Q/K/Vt ----------------

__global__ __launch_bounds__(256) void gemm_qkv(
    const bf16* __restrict__ A, const bf16* __restrict__ Bt,
    const float* __restrict__ bias,
    bf16* __restrict__ Qo, bf16* __restrict__ Ko, bf16* __restrict__ Vt) {
    __shared__ __align__(16) bf16 As[128 * 32];
    __shared__ __align__(16) bf16 Bs[128 * 32];
    const int t = threadIdx.x;
    const int lane = t & 63, wave = t >> 6;
    const int l15 = lane & 15, quad = lane >> 4;
    const int wm = wave & 1, wn = wave >> 1;
    const int m0 = blockIdx.y * 128, n0 = blockIdx.x * 128;

    f32x4 acc[4][4] = {};

    const bf16* ag = A + (m0 + (t >> 2)) * 1024 + (t & 3) * 8;
    const bf16* bg = Bt + (n0 + (t >> 2)) * 1024 + (t & 3) * 8;
    bf16* as0 = As + wave * 512;
    bf16* as1 = As + 2048 + wave * 512;
    bf16* bs0 = Bs + wave * 512;
    bf16* bs1 = Bs + 2048 + wave * 512;

    for (int k0 = 0; k0 < 1024; k0 += 32) {
        async16(ag + k0, as0);
        async16(ag + 64 * 1024 + k0, as1);
        async16(bg + k0, bs0);
        async16(bg + 64 * 1024 + k0, bs1);
        __syncthreads();
        bf16x8 af[4], bfr[4];
        for (int i = 0; i < 4; i++)
            af[i] = *(const bf16x8*)(As + (wm * 64 + i * 16 + l15) * 32 + quad * 8);
        for (int j = 0; j < 4; j++)
            bfr[j] = *(const bf16x8*)(Bs + (wn * 64 + j * 16 + l15) * 32 + quad * 8);
        for (int i = 0; i < 4; i++)
            for (int j = 0; j < 4; j++)
                acc[i][j] = __builtin_amdgcn_mfma_f32_16x16x32_bf16(af[i], bfr[j], acc[i][j], 0, 0, 0);
        __syncthreads();
    }

    for (int i = 0; i < 4; i++) {
        for (int j = 0; j < 4; j++) {
            int col = n0 + wn * 64 + j * 16 + l15;
            float bv = bias[col];
            int sec = col >> 10, c2 = col & 1023, h = c2 >> 6, d = c2 & 63;
            for (int r = 0; r < 4; r++) {
                int row = m0 + wm * 64 + i * 16 + quad * 4 + r;
                int b = row >> 11, tt = row & 2047;
                int bh = b * NHEAD + h;
                float v = acc[i][j][r] + bv;
                if (sec == 0)
                    Qo[(bh * T_SEQ + tt) * 64 + d] = (bf16)(v * QSCALE);
                else if (sec == 1)
                    Ko[(bh * T_SEQ + tt) * 64 + d] = (bf16)v;
                else
                    Vt[(bh * 64 + d) * T_SEQ + tt] = (bf16)v;
            }
        }
    }
}

// ---------------- attention ----------------
// 256 blocks x 512 thr. Block: tile pair {15-pr, pr} (128 rows each) of one
// bh, processed sequentially -> 34 chunk-stages per block, uniform.
#define PSTR 64
__global__ __launch_bounds__(512, 2) void attn(
    const bf16* __restrict__ Q, const bf16* __restrict__ K,
    const bf16* __restrict__ Vt, bf16* __restrict__ AO) {
    __shared__ __align__(16) bf16 Ks[2][64 * 64];
    __shared__ __align__(16) bf16 Vs[2][64 * 64];
    __shared__ __align__(16) bf16 Pb[8][16 * PSTR];
    const int tid = threadIdx.x;
    const int lane = tid & 63, wave = tid >> 6;
    const int l15 = lane & 15, quad = lane >> 4;
    const int bh = ((blockIdx.x & 7) << 2) | ((blockIdx.x >> 3) & 3);
    const int pr = blockIdx.x >> 5;  // 0..7 -> tile pair {15-pr, pr}

    const bf16* kp = K + bh * T_SEQ * 64;
    const bf16* vp = Vt + bh * 64 * T_SEQ;
    bf16* pw = &Pb[wave][0];
    const int b_ = bh >> 4, h_ = bh & 15;

    // frag-read swizzle offset (granule p = quad ^ (row&7), row&7 == l15&7)
    const int sx = (quad ^ (l15 & 7)) << 3;

    // stage chunk (keys kb..kb+63, kb in KEY units) into buffer b
    auto stage = [&](int kb, int b) {
        int rowi = tid >> 3, p = tid & 7;
        const bf16* ksrc = kp + (kb + rowi) * 64 + ((p ^ (rowi & 7)) << 3);
        async16(ksrc, &Ks[b][wave * 512]);
        const bf16* vsrc = vp + rowi * T_SEQ + kb + ((p ^ (rowi & 7)) << 3);
        async16(vsrc, &Vs[b][wave * 512]);
    };

    for (int half = 0; half < 2; half++) {
        const int qt = half ? pr : (15 - pr);   // big tile first
        const int t0 = qt * 128 + wave * 16;
        const int m = t0 >> 4;
        const bf16* qp = Q + (bh * T_SEQ + t0) * 64;
        bf16x8 qf0 = *(const bf16x8*)(qp + l15 * 64 + quad * 8);
        bf16x8 qf1 = *(const bf16x8*)(qp + l15 * 64 + 32 + quad * 8);

        f32x4 acc[4] = {};
        float lsum[4] = {0.f, 0.f, 0.f, 0.f};

        const int C = 2 * qt + 2;  // 64-key chunks this tile needs
        stage(0, 0);
        for (int c = 0; c < C; c++) {
            __syncthreads();  // stage(c) complete, all waves aligned
            if (c + 1 < C) stage((c + 1) * 64, (c + 1) & 1);  // KEY units (R5 bug)
            const int nr = m - 4 * c + 1;  // raw active-subtile count
            if (nr > 0) {
                const int na = min(4, nr);
                const bool dg = (nr <= 4);  // last active subtile is diagonal
                const bf16* ksb = &Ks[c & 1][0];
                const bf16* vsb = &Vs[c & 1][0];

                f32x4 sc[4];
                for (int n = 0; n < 4; n++) {
                    if (n < na) {
                        const bf16* kbase = ksb + (n * 16 + l15) * 64;
                        bf16x8 kf0 = *(const bf16x8*)(kbase + sx);
                        bf16x8 kf1 = *(const bf16x8*)(kbase + (sx ^ 32));
                        f32x4 z = {};
                        z = __builtin_amdgcn_mfma_f32_16x16x32_bf16(qf0, kf0, z, 0, 0, 0);
                        z = __builtin_amdgcn_mfma_f32_16x16x32_bf16(qf1, kf1, z, 0, 0, 0);
                        sc[n] = z;
                    }
                }
                for (int n = 0; n < 4; n++) {
                    for (int r = 0; r < 4; r++) {
                        float e = 0.0f;
                        if (n < na) {
                            float v = sc[n][r];
                            if (dg && n == na - 1) {
                                int key = c * 64 + n * 16 + l15;
                                int qrow = t0 + quad * 4 + r;
                                if (key > qrow) v = -100000.0f;
                            }
                            e = __builtin_amdgcn_exp2f(v);
                        }
                        lsum[r] += e;
                        pw[(quad * 4 + r) * PSTR + n * 16 + l15] = (bf16)e;
                    }
                }
                // lgkmcnt(0) only: P round-trip ordering w/o draining vmcnt
                __builtin_amdgcn_s_waitcnt(0xC07F);
                bf16x8 pf0 = *(const bf16x8*)(pw + l15 * PSTR + quad * 8);
                bf16x8 pf1 = *(const bf16x8*)(pw + l15 * PSTR + 32 + quad * 8);
                for (int j = 0; j < 4; j++) {
                    const bf16* vbase = vsb + (j * 16 + l15) * 64;
                    bf16x8 vf0 = *(const bf16x8*)(vbase + sx);
                    bf16x8 vf1 = *(const bf16x8*)(vbase + (sx ^ 32));
                    acc[j] = __builtin_amdgcn_mfma_f32_16x16x32_bf16(pf0, vf0, acc[j], 0, 0, 0);
                    acc[j] = __builtin_amdgcn_mfma_f32_16x16x32_bf16(pf1, vf1, acc[j], 0, 0, 0);
                }
            }
        }

        float linv[4];
        for (int r = 0; r < 4; r++) {
            float v = lsum[r];
            v += __shfl_xor(v, 1, 16);
            v += __shfl_xor(v, 2, 16);
            v += __shfl_xor(v, 4, 16);
            v += __shfl_xor(v, 8, 16);
            linv[r] = 1.0f / v;
        }
        bf16* aop = AO + (b_ * T_SEQ + t0) * 1024 + h_ * 64;
        for (int r = 0; r < 4; r++)
            for (int j = 0; j < 4; j++)
                aop[(quad * 4 + r) * 1024 + j * 16 + l15] = (bf16)(acc[j][r] * linv[r]);
        // next half's stage(0,buf0) is safe without a barrier: buf0's last
        // readers (chunk C-2) finished before the barrier at top of chunk C-1
        // (C even), and chunk C-1 reads only buf1.
    }
}

// ---------------- GEMM 2: out = AO @ out_w + out_b (fp32 out) ----------------
__global__ __launch_bounds__(256) void gemm_out_k(
    const bf16* __restrict__ A, const bf16* __restrict__ Bt,
    const float* __restrict__ bias, float* __restrict__ out) {
    __shared__ __align__(16) bf16 As[128 * 32];
    __shared__ __align__(16) bf16 Bs[128 * 32];
    const int t = threadIdx.x;
    const int lane = t & 63, wave = t >> 6;
    const int l15 = lane & 15, quad = lane >> 4;
    const int wm = wave & 1, wn = wave >> 1;
    const int m0 = blockIdx.y * 128, n0 = blockIdx.x * 128;

    f32x4 acc[4][4] = {};

    const bf16* ag = A + (m0 + (t >> 2)) * 1024 + (t & 3) * 8;
    const bf16* bg = Bt + (n0 + (t >> 2)) * 1024 + (t & 3) * 8;
    bf16* as0 = As + wave * 512;
    bf16* as1 = As + 2048 + wave * 512;
    bf16* bs0 = Bs + wave * 512;
    bf16* bs1 = Bs + 2048 + wave * 512;

    for (int k0 = 0; k0 < 1024; k0 += 32) {
        async16(ag + k0, as0);
        async16(ag + 64 * 1024 + k0, as1);
        async16(bg + k0, bs0);
        async16(bg + 64 * 1024 + k0, bs1);
        __syncthreads();
        bf16x8 af[4], bfr[4];
        for (int i = 0; i < 4; i++)
            af[i] = *(const bf16x8*)(As + (wm * 64 + i * 16 + l15) * 32 + quad * 8);
        for (int j = 0; j < 4; j++)
            bfr[j] = *(const bf16x8*)(Bs + (wn * 64 + j * 16 + l15) * 32 + quad * 8);
        for (int i = 0; i < 4; i++)
            for (int j = 0; j < 4; j++)
                acc[i][j] = __builtin_amdgcn_mfma_f32_16x16x32_bf16(af[i], bfr[j], acc[i][j], 0, 0, 0);
        __syncthreads();
    }

    for (int i = 0; i < 4; i++) {
        for (int j = 0; j < 4; j++) {
            int col = n0 + wn * 64 + j * 16 + l15;
            float bv = bias[col];
            for (int r = 0; r < 4; r++) {
                int row = m0 + wm * 64 + i * 16 + quad * 4 + r;
                out[row * 1024 + col] = acc[i][j][r] + bv;
            }
        }
    }
}

// ---------------- launch ----------------
extern "C" void kernel_launch(void* const* d_in, const int* in_sizes, int n_in,
                              void* d_out, int out_size, void* d_ws, size_t ws_size,
                              hipStream_t stream) {
    const float* x     = (const float*)d_in[0];
    const float* qkv_w = (const float*)d_in[1];
    const float* qkv_b = (const float*)d_in[2];
    const float* out_w = (const float*)d_in[3];
    const float* out_b = (const float*)d_in[4];
    float* out = (float*)d_out;

    char* ws = (char*)d_ws;
    bf16* xb   = (bf16*)(ws);                     // 8 MB
    bf16* wbT  = (bf16*)(ws + (8ull << 20));      // 6 MB  (3072 x 1024)
    bf16* owbT = (bf16*)(ws + (14ull << 20));     // 2 MB  (1024 x 1024)
    bf16* Qb   = (bf16*)(ws + (16ull << 20));     // 8 MB  (B,H,T,Dh), pre-scaled
    bf16* Kb   = (bf16*)(ws + (24ull << 20));     // 8 MB  (B,H,T,Dh)
    bf16* Vt   = (bf16*)(ws + (32ull << 20));     // 8 MB  (B,H,Dh,T)
    bf16* AO   = (bf16*)(ws + (40ull << 20));     // 8 MB  (B,T,C)

    prep<<<8192, 256, 0, stream>>>(x, xb, qkv_w, wbT, out_w, owbT);
    gemm_qkv<<<dim3(24, 32), 256, 0, stream>>>(xb, wbT, qkv_b, Qb, Kb, Vt);
    attn<<<256, 512, 0, stream>>>(Qb, Kb, Vt, AO);
    gemm_out_k<<<dim3(8, 32), 256, 0, stream>>>(AO, owbT, out_b, out);
}

// Round 7
// 188.227 us; speedup vs baseline: 1.4857x; 1.0755x over previous
//
#include <hip/hip_runtime.h>

// Causal MHSA: B=2, T=2048, C=1024, H=16, Dh=64.
// prep -> QKV GEMM -> flash attn -> out GEMM.
//
// R7 attn: S^T orientation. Scores computed as S^T = K·Q^T (swap MFMA
// operands) so each lane holds 4 P values along KEY with query fixed = l15.
// P then goes to LDS via ONE ds_write_b64 per 16-key subtile directly in the
// PV A-operand layout (row=query=l15, keys contiguous) and comes back as two
// ds_read_b128 A-frags. Eliminates the 16 scalar conflicted P stores/chunk
// (R6's 3.78M conflict cycles). Diagonal mask is position-only
// (quad*4+r > l15); row-sum is one scalar/lane + 2 shuffles. O exits in the
// original (row=query, col=d) layout -> epilogue unchanged.
// Grid: 1024 blocks x 256 thr (one 64-row tile), LDS 43 KB -> 3 blocks/CU
// co-resident; qt big/small interleaved in dispatch order.

typedef __bf16 bf16;
typedef __attribute__((ext_vector_type(4))) __bf16 bf16x4;
typedef __attribute__((ext_vector_type(8))) __bf16 bf16x8;
typedef __attribute__((ext_vector_type(4))) float f32x4;

#define T_SEQ 2048
#define NHEAD 16
#define QSCALE 0.1803368801111244f  // log2(e)/sqrt(64)

__device__ __forceinline__ void async16(const bf16* g, const bf16* l) {
    __builtin_amdgcn_global_load_lds(
        (const __attribute__((address_space(1))) void*)g,
        (__attribute__((address_space(3))) void*)l, 16, 0, 0);
}

// ---------------- fused prep ----------------
__global__ __launch_bounds__(256) void prep(
    const float* __restrict__ x, bf16* __restrict__ xb,
    const float* __restrict__ qkv_w, bf16* __restrict__ wbT,
    const float* __restrict__ out_w, bf16* __restrict__ owbT) {
    const int bid = blockIdx.x, tid = threadIdx.x;
    if (bid < 4096) {
        int i = (bid * 256 + tid) * 4;
        float4 v = *(const float4*)(x + i);
        bf16x4 o;
        o.x = (bf16)v.x; o.y = (bf16)v.y; o.z = (bf16)v.z; o.w = (bf16)v.w;
        *(bf16x4*)(xb + i) = o;
        return;
    }
    __shared__ float tile[32][33];
    const float* in;
    bf16* out;
    int K_, N_, b;
    if (bid < 7168) { b = bid - 4096; in = qkv_w; out = wbT; K_ = 1024; N_ = 3072; }
    else            { b = bid - 7168; in = out_w; out = owbT; K_ = 1024; N_ = 1024; }
    int k0 = (b & 31) * 32, n0 = (b >> 5) * 32;
    int tx = tid & 31, ty = tid >> 5;
    for (int r = 0; r < 32; r += 8)
        tile[ty + r][tx] = in[(k0 + ty + r) * N_ + n0 + tx];
    __syncthreads();
    for (int r = 0; r < 32; r += 8)
        out[(n0 + ty + r) * K_ + k0 + tx] = (bf16)tile[tx][ty + r];
}

// ---------------- GEMM 1: qkv = x @ qkv_w + b, scatter to Q/K/Vt ----------------
__global__ __launch_bounds__(256) void gemm_qkv(
    const bf16* __restrict__ A, const bf16* __restrict__ Bt,
    const float* __restrict__ bias,
    bf16* __restrict__ Qo, bf16* __restrict__ Ko, bf16* __restrict__ Vt) {
    __shared__ __align__(16) bf16 As[128 * 32];
    __shared__ __align__(16) bf16 Bs[128 * 32];
    const int t = threadIdx.x;
    const int lane = t & 63, wave = t >> 6;
    const int l15 = lane & 15, quad = lane >> 4;
    const int wm = wave & 1, wn = wave >> 1;
    const int m0 = blockIdx.y * 128, n0 = blockIdx.x * 128;

    f32x4 acc[4][4] = {};

    const bf16* ag = A + (m0 + (t >> 2)) * 1024 + (t & 3) * 8;
    const bf16* bg = Bt + (n0 + (t >> 2)) * 1024 + (t & 3) * 8;
    bf16* as0 = As + wave * 512;
    bf16* as1 = As + 2048 + wave * 512;
    bf16* bs0 = Bs + wave * 512;
    bf16* bs1 = Bs + 2048 + wave * 512;

    for (int k0 = 0; k0 < 1024; k0 += 32) {
        async16(ag + k0, as0);
        async16(ag + 64 * 1024 + k0, as1);
        async16(bg + k0, bs0);
        async16(bg + 64 * 1024 + k0, bs1);
        __syncthreads();
        bf16x8 af[4], bfr[4];
        for (int i = 0; i < 4; i++)
            af[i] = *(const bf16x8*)(As + (wm * 64 + i * 16 + l15) * 32 + quad * 8);
        for (int j = 0; j < 4; j++)
            bfr[j] = *(const bf16x8*)(Bs + (wn * 64 + j * 16 + l15) * 32 + quad * 8);
        for (int i = 0; i < 4; i++)
            for (int j = 0; j < 4; j++)
                acc[i][j] = __builtin_amdgcn_mfma_f32_16x16x32_bf16(af[i], bfr[j], acc[i][j], 0, 0, 0);
        __syncthreads();
    }

    for (int i = 0; i < 4; i++) {
        for (int j = 0; j < 4; j++) {
            int col = n0 + wn * 64 + j * 16 + l15;
            float bv = bias[col];
            int sec = col >> 10, c2 = col & 1023, h = c2 >> 6, d = c2 & 63;
            for (int r = 0; r < 4; r++) {
                int row = m0 + wm * 64 + i * 16 + quad * 4 + r;
                int b = row >> 11, tt = row & 2047;
                int bh = b * NHEAD + h;
                float v = acc[i][j][r] + bv;
                if (sec == 0)
                    Qo[(bh * T_SEQ + tt) * 64 + d] = (bf16)(v * QSCALE);
                else if (sec == 1)
                    Ko[(bh * T_SEQ + tt) * 64 + d] = (bf16)v;
                else
                    Vt[(bh * 64 + d) * T_SEQ + tt] = (bf16)v;
            }
        }
    }
}

// ---------------- attention ----------------
// 1024 blocks x 256 thr. Block: one 64-row Q-tile (4 waves x 16 rows) of one
// bh; chunks of 64 keys staged to LDS (double-buffered). qt interleaved
// big/small in dispatch order; bh grouped per XCD residue (blockIdx&7).
#define PST 80  // Pa row stride (elems): banks spread ~uniform for b64/b128
__global__ __launch_bounds__(256, 4) void attn(
    const bf16* __restrict__ Q, const bf16* __restrict__ K,
    const bf16* __restrict__ Vt, bf16* __restrict__ AO) {
    __shared__ __align__(16) bf16 Ks[2][64 * 64];
    __shared__ __align__(16) bf16 Vs[2][64 * 64];
    __shared__ __align__(16) bf16 Pa[4][16 * PST];
    const int tid = threadIdx.x;
    const int lane = tid & 63, wave = tid >> 6;
    const int l15 = lane & 15, quad = lane >> 4;
    const int xcdr = blockIdx.x & 7;
    const int i_ = blockIdx.x >> 3;          // 0..127
    const int bh = (xcdr << 2) | (i_ & 3);   // 4 bh per XCD residue
    const int ti = i_ >> 2;                  // 0..31
    const int qt = (ti & 1) ? (ti >> 1) : (31 - (ti >> 1));  // big/small mix
    const int t0w = qt * 64 + wave * 16;     // this wave's first query row

    const bf16* kp = K + bh * T_SEQ * 64;
    const bf16* vp = Vt + bh * 64 * T_SEQ;
    bf16* pw = &Pa[wave][0];
    const int b_ = bh >> 4, h_ = bh & 15;

    // K/V frag-read swizzle (phys granule = logical ^ (row&7))
    const int sx = (quad ^ (l15 & 7)) << 3;

    const bf16* qp = Q + (bh * T_SEQ + t0w) * 64;
    bf16x8 qf0 = *(const bf16x8*)(qp + l15 * 64 + quad * 8);
    bf16x8 qf1 = *(const bf16x8*)(qp + l15 * 64 + 32 + quad * 8);

    // stage chunk (keys kb..kb+63) into buffer b: 2 async16/thread/operand
    auto stage = [&](int kb, int b) {
        for (int i = 0; i < 2; i++) {
            int row = i * 32 + (tid >> 3), p = tid & 7;
            const bf16* ksrc = kp + (kb + row) * 64 + ((p ^ (row & 7)) << 3);
            async16(ksrc, &Ks[b][i * 2048 + wave * 512]);
            const bf16* vsrc = vp + row * T_SEQ + kb + ((p ^ (row & 7)) << 3);
            async16(vsrc, &Vs[b][i * 2048 + wave * 512]);
        }
    };

    f32x4 acc[4] = {};
    float lsum = 0.0f;

    const int C = qt + 1;
    stage(0, 0);
    for (int c = 0; c < C; c++) {
        __syncthreads();  // stage(c) landed; all waves aligned
        if (c + 1 < C) stage((c + 1) * 64, (c + 1) & 1);
        const bf16* ksb = &Ks[c & 1][0];
        const bf16* vsb = &Vs[c & 1][0];
        const bool dg = (c == qt);
        const int na = dg ? (wave + 1) : 4;  // active 16-key subtiles

        // S^T: A = K-frag (m=key), B = Q-frag (n=query)
        f32x4 sc[4];
        for (int n = 0; n < 4; n++) {
            if (n < na) {
                const bf16* kbase = ksb + (n * 16 + l15) * 64;
                bf16x8 kf0 = *(const bf16x8*)(kbase + sx);
                bf16x8 kf1 = *(const bf16x8*)(kbase + (sx ^ 32));
                f32x4 z = {};
                z = __builtin_amdgcn_mfma_f32_16x16x32_bf16(kf0, qf0, z, 0, 0, 0);
                z = __builtin_amdgcn_mfma_f32_16x16x32_bf16(kf1, qf1, z, 0, 0, 0);
                sc[n] = z;
            }
        }
        // exp2 + pack 4 keys -> one b64 store per subtile, PV A-layout
        for (int n = 0; n < 4; n++) {
            bf16x4 pv;
            if (n < na) {
                const bool dmask = dg && (n == na - 1);  // diagonal subtile
                for (int r = 0; r < 4; r++) {
                    float v = sc[n][r];
                    if (dmask && (quad * 4 + r > l15)) v = -100000.0f;
                    float e = __builtin_amdgcn_exp2f(v);
                    lsum += e;
                    pv[r] = (bf16)e;
                }
            } else {
                pv[0] = pv[1] = pv[2] = pv[3] = (bf16)0.0f;
            }
            *(bf16x4*)(pw + l15 * PST + n * 16 + quad * 4) = pv;
        }
        __builtin_amdgcn_s_waitcnt(0xC07F);  // lgkm only; vmcnt stays in flight
        // PV: A = P-frag (m=query), B = V-frag (n=d)
        for (int g = 0; g < 2; g++) {
            bf16x8 pf = *(const bf16x8*)(pw + l15 * PST + g * 32 + quad * 8);
            for (int j = 0; j < 4; j++) {
                const bf16* vbase = vsb + (j * 16 + l15) * 64;
                bf16x8 vf = *(const bf16x8*)(vbase + (g ? (sx ^ 32) : sx));
                acc[j] = __builtin_amdgcn_mfma_f32_16x16x32_bf16(pf, vf, acc[j], 0, 0, 0);
            }
        }
    }

    // row-sum: lane holds partial for query=l15; sum the 4 quads
    lsum += __shfl_xor(lsum, 16);
    lsum += __shfl_xor(lsum, 32);
    float linv = 1.0f / lsum;

    bf16* aop = AO + (b_ * T_SEQ + t0w) * 1024 + h_ * 64;
    for (int r = 0; r < 4; r++) {
        float lr = __shfl(linv, quad * 4 + r, 16);  // linv for query quad*4+r
        for (int j = 0; j < 4; j++)
            aop[(quad * 4 + r) * 1024 + j * 16 + l15] = (bf16)(acc[j][r] * lr);
    }
}

// ---------------- GEMM 2: out = AO @ out_w + out_b (fp32 out) ----------------
__global__ __launch_bounds__(256) void gemm_out_k(
    const bf16* __restrict__ A, const bf16* __restrict__ Bt,
    const float* __restrict__ bias, float* __restrict__ out) {
    __shared__ __align__(16) bf16 As[128 * 32];
    __shared__ __align__(16) bf16 Bs[128 * 32];
    const int t = threadIdx.x;
    const int lane = t & 63, wave = t >> 6;
    const int l15 = lane & 15, quad = lane >> 4;
    const int wm = wave & 1, wn = wave >> 1;
    const int m0 = blockIdx.y * 128, n0 = blockIdx.x * 128;

    f32x4 acc[4][4] = {};

    const bf16* ag = A + (m0 + (t >> 2)) * 1024 + (t & 3) * 8;
    const bf16* bg = Bt + (n0 + (t >> 2)) * 1024 + (t & 3) * 8;
    bf16* as0 = As + wave * 512;
    bf16* as1 = As + 2048 + wave * 512;
    bf16* bs0 = Bs + wave * 512;
    bf16* bs1 = Bs + 2048 + wave * 512;

    for (int k0 = 0; k0 < 1024; k0 += 32) {
        async16(ag + k0, as0);
        async16(ag + 64 * 1024 + k0, as1);
        async16(bg + k0, bs0);
        async16(bg + 64 * 1024 + k0, bs1);
        __syncthreads();
        bf16x8 af[4], bfr[4];
        for (int i = 0; i < 4; i++)
            af[i] = *(const bf16x8*)(As + (wm * 64 + i * 16 + l15) * 32 + quad * 8);
        for (int j = 0; j < 4; j++)
            bfr[j] = *(const bf16x8*)(Bs + (wn * 64 + j * 16 + l15) * 32 + quad * 8);
        for (int i = 0; i < 4; i++)
            for (int j = 0; j < 4; j++)
                acc[i][j] = __builtin_amdgcn_mfma_f32_16x16x32_bf16(af[i], bfr[j], acc[i][j], 0, 0, 0);
        __syncthreads();
    }

    for (int i = 0; i < 4; i++) {
        for (int j = 0; j < 4; j++) {
            int col = n0 + wn * 64 + j * 16 + l15;
            float bv = bias[col];
            for (int r = 0; r < 4; r++) {
                int row = m0 + wm * 64 + i * 16 + quad * 4 + r;
                out[row * 1024 + col] = acc[i][j][r] + bv;
            }
        }
    }
}

// ---------------- launch ----------------
extern "C" void kernel_launch(void* const* d_in, const int* in_sizes, int n_in,
                              void* d_out, int out_size, void* d_ws, size_t ws_size,
                              hipStream_t stream) {
    const float* x     = (const float*)d_in[0];
    const float* qkv_w = (const float*)d_in[1];
    const float* qkv_b = (const float*)d_in[2];
    const float* out_w = (const float*)d_in[3];
    const float* out_b = (const float*)d_in[4];
    float* out = (float*)d_out;

    char* ws = (char*)d_ws;
    bf16* xb   = (bf16*)(ws);                     // 8 MB
    bf16* wbT  = (bf16*)(ws + (8ull << 20));      // 6 MB
    bf16* owbT = (bf16*)(ws + (14ull << 20));     // 2 MB
    bf16* Qb   = (bf16*)(ws + (16ull << 20));     // 8 MB (B,H,T,Dh), pre-scaled
    bf16* Kb   = (bf16*)(ws + (24ull << 20));     // 8 MB (B,H,T,Dh)
    bf16* Vt   = (bf16*)(ws + (32ull << 20));     // 8 MB (B,H,Dh,T)
    bf16* AO   = (bf16*)(ws + (40ull << 20));     // 8 MB (B,T,C)

    prep<<<8192, 256, 0, stream>>>(x, xb, qkv_w, wbT, out_w, owbT);
    gemm_qkv<<<dim3(24, 32), 256, 0, stream>>>(xb, wbT, qkv_b, Qb, Kb, Vt);
    attn<<<1024, 256, 0, stream>>>(Qb, Kb, Vt, AO);
    gemm_out_k<<<dim3(8, 32), 256, 0, stream>>>(AO, owbT, out_b, out);
}

// Round 8
// 176.641 us; speedup vs baseline: 1.5832x; 1.0656x over previous
//
#include <hip/hip_runtime.h>

// Causal MHSA: B=2, T=2048, C=1024, H=16, Dh=64.
// prep -> QKV GEMM -> flash attn (S^T orientation) -> out GEMM.
//
// R8: epilogue-oriented GEMMs.
// gemm_qkv: each 128-col block is pure Q, K, or V (1024%128==0). Q/K blocks
// compute C^T via swapped MFMA operands -> lane holds 4 consecutive d values
// -> b64 stores (16/thread) + float4 bias loads. V blocks keep normal
// orientation -> 4 consecutive t values -> b64 stores into Vt. Replaces 64
// scalar 2B stores + 64 addr computations per thread.
// gemm_out: 64x128 tiles -> 512 blocks (2/CU, was 1/CU), swapped orientation
// -> float4 stores.

typedef __bf16 bf16;
typedef __attribute__((ext_vector_type(4))) __bf16 bf16x4;
typedef __attribute__((ext_vector_type(8))) __bf16 bf16x8;
typedef __attribute__((ext_vector_type(4))) float f32x4;

#define T_SEQ 2048
#define NHEAD 16
#define QSCALE 0.1803368801111244f  // log2(e)/sqrt(64)

__device__ __forceinline__ void async16(const bf16* g, const bf16* l) {
    __builtin_amdgcn_global_load_lds(
        (const __attribute__((address_space(1))) void*)g,
        (__attribute__((address_space(3))) void*)l, 16, 0, 0);
}

// ---------------- fused prep ----------------
__global__ __launch_bounds__(256) void prep(
    const float* __restrict__ x, bf16* __restrict__ xb,
    const float* __restrict__ qkv_w, bf16* __restrict__ wbT,
    const float* __restrict__ out_w, bf16* __restrict__ owbT) {
    const int bid = blockIdx.x, tid = threadIdx.x;
    if (bid < 4096) {
        int i = (bid * 256 + tid) * 4;
        float4 v = *(const float4*)(x + i);
        bf16x4 o;
        o.x = (bf16)v.x; o.y = (bf16)v.y; o.z = (bf16)v.z; o.w = (bf16)v.w;
        *(bf16x4*)(xb + i) = o;
        return;
    }
    __shared__ float tile[32][33];
    const float* in;
    bf16* out;
    int K_, N_, b;
    if (bid < 7168) { b = bid - 4096; in = qkv_w; out = wbT; K_ = 1024; N_ = 3072; }
    else            { b = bid - 7168; in = out_w; out = owbT; K_ = 1024; N_ = 1024; }
    int k0 = (b & 31) * 32, n0 = (b >> 5) * 32;
    int tx = tid & 31, ty = tid >> 5;
    for (int r = 0; r < 32; r += 8)
        tile[ty + r][tx] = in[(k0 + ty + r) * N_ + n0 + tx];
    __syncthreads();
    for (int r = 0; r < 32; r += 8)
        out[(n0 + ty + r) * K_ + k0 + tx] = (bf16)tile[tx][ty + r];
}

// ---------------- GEMM 1: qkv = x @ qkv_w + b, scatter to Q/K/Vt ----------------
__global__ __launch_bounds__(256) void gemm_qkv(
    const bf16* __restrict__ A, const bf16* __restrict__ Bt,
    const float* __restrict__ bias,
    bf16* __restrict__ Qo, bf16* __restrict__ Ko, bf16* __restrict__ Vt) {
    __shared__ __align__(16) bf16 As[128 * 32];
    __shared__ __align__(16) bf16 Bs[128 * 32];
    const int t = threadIdx.x;
    const int lane = t & 63, wave = t >> 6;
    const int l15 = lane & 15, quad = lane >> 4;
    const int wm = wave & 1, wn = wave >> 1;
    const int m0 = blockIdx.y * 128, n0 = blockIdx.x * 128;
    const int sec = n0 >> 10;  // block-uniform: 0=Q, 1=K, 2=V

    f32x4 acc[4][4] = {};

    const bf16* ag = A + (m0 + (t >> 2)) * 1024 + (t & 3) * 8;
    const bf16* bg = Bt + (n0 + (t >> 2)) * 1024 + (t & 3) * 8;
    bf16* as0 = As + wave * 512;
    bf16* as1 = As + 2048 + wave * 512;
    bf16* bs0 = Bs + wave * 512;
    bf16* bs1 = Bs + 2048 + wave * 512;

    if (sec < 2) {
        // ---- swapped orientation: acc[j][i] = C^T (row=feature, col=t) ----
        for (int k0 = 0; k0 < 1024; k0 += 32) {
            async16(ag + k0, as0);
            async16(ag + 64 * 1024 + k0, as1);
            async16(bg + k0, bs0);
            async16(bg + 64 * 1024 + k0, bs1);
            __syncthreads();
            bf16x8 af[4], bfr[4];
            for (int i = 0; i < 4; i++)
                af[i] = *(const bf16x8*)(As + (wm * 64 + i * 16 + l15) * 32 + quad * 8);
            for (int j = 0; j < 4; j++)
                bfr[j] = *(const bf16x8*)(Bs + (wn * 64 + j * 16 + l15) * 32 + quad * 8);
            for (int j = 0; j < 4; j++)
                for (int i = 0; i < 4; i++)
                    acc[j][i] = __builtin_amdgcn_mfma_f32_16x16x32_bf16(bfr[j], af[i], acc[j][i], 0, 0, 0);
            __syncthreads();
        }
        bf16* dst = (sec == 0) ? Qo : Ko;
        const float sc = (sec == 0) ? QSCALE : 1.0f;
        for (int j = 0; j < 4; j++) {
            int col0 = n0 + wn * 64 + j * 16 + quad * 4;  // 4 consecutive feats
            float4 bv = *(const float4*)(bias + col0);
            int c2 = col0 & 1023, h = c2 >> 6, d0 = c2 & 63;  // d0..d0+3 same h
            for (int i = 0; i < 4; i++) {
                int row = m0 + wm * 64 + i * 16 + l15;
                int b = row >> 11, tt = row & 2047;
                int bh = b * NHEAD + h;
                bf16x4 o;
                o[0] = (bf16)((acc[j][i][0] + bv.x) * sc);
                o[1] = (bf16)((acc[j][i][1] + bv.y) * sc);
                o[2] = (bf16)((acc[j][i][2] + bv.z) * sc);
                o[3] = (bf16)((acc[j][i][3] + bv.w) * sc);
                *(bf16x4*)(dst + (bh * T_SEQ + tt) * 64 + d0) = o;
            }
        }
    } else {
        // ---- normal orientation: acc[i][j] (row=t, col=feature) -> Vt ----
        for (int k0 = 0; k0 < 1024; k0 += 32) {
            async16(ag + k0, as0);
            async16(ag + 64 * 1024 + k0, as1);
            async16(bg + k0, bs0);
            async16(bg + 64 * 1024 + k0, bs1);
            __syncthreads();
            bf16x8 af[4], bfr[4];
            for (int i = 0; i < 4; i++)
                af[i] = *(const bf16x8*)(As + (wm * 64 + i * 16 + l15) * 32 + quad * 8);
            for (int j = 0; j < 4; j++)
                bfr[j] = *(const bf16x8*)(Bs + (wn * 64 + j * 16 + l15) * 32 + quad * 8);
            for (int i = 0; i < 4; i++)
                for (int j = 0; j < 4; j++)
                    acc[i][j] = __builtin_amdgcn_mfma_f32_16x16x32_bf16(af[i], bfr[j], acc[i][j], 0, 0, 0);
            __syncthreads();
        }
        for (int j = 0; j < 4; j++) {
            int col = n0 + wn * 64 + j * 16 + l15;
            float bv = bias[col];
            int c2 = col & 1023, h = c2 >> 6, d = c2 & 63;
            for (int i = 0; i < 4; i++) {
                int row0 = m0 + wm * 64 + i * 16 + quad * 4;  // 4 consecutive t
                int b = row0 >> 11, tt0 = row0 & 2047;
                int bh = b * NHEAD + h;
                bf16x4 o;
                for (int r = 0; r < 4; r++)
                    o[r] = (bf16)(acc[i][j][r] + bv);
                *(bf16x4*)(Vt + (bh * 64 + d) * T_SEQ + tt0) = o;
            }
        }
    }
}

// ---------------- attention (R7, unchanged) ----------------
#define PST 80
__global__ __launch_bounds__(256, 4) void attn(
    const bf16* __restrict__ Q, const bf16* __restrict__ K,
    const bf16* __restrict__ Vt, bf16* __restrict__ AO) {
    __shared__ __align__(16) bf16 Ks[2][64 * 64];
    __shared__ __align__(16) bf16 Vs[2][64 * 64];
    __shared__ __align__(16) bf16 Pa[4][16 * PST];
    const int tid = threadIdx.x;
    const int lane = tid & 63, wave = tid >> 6;
    const int l15 = lane & 15, quad = lane >> 4;
    const int xcdr = blockIdx.x & 7;
    const int i_ = blockIdx.x >> 3;
    const int bh = (xcdr << 2) | (i_ & 3);
    const int ti = i_ >> 2;
    const int qt = (ti & 1) ? (ti >> 1) : (31 - (ti >> 1));
    const int t0w = qt * 64 + wave * 16;

    const bf16* kp = K + bh * T_SEQ * 64;
    const bf16* vp = Vt + bh * 64 * T_SEQ;
    bf16* pw = &Pa[wave][0];
    const int b_ = bh >> 4, h_ = bh & 15;

    const int sx = (quad ^ (l15 & 7)) << 3;

    const bf16* qp = Q + (bh * T_SEQ + t0w) * 64;
    bf16x8 qf0 = *(const bf16x8*)(qp + l15 * 64 + quad * 8);
    bf16x8 qf1 = *(const bf16x8*)(qp + l15 * 64 + 32 + quad * 8);

    auto stage = [&](int kb, int b) {
        for (int i = 0; i < 2; i++) {
            int row = i * 32 + (tid >> 3), p = tid & 7;
            const bf16* ksrc = kp + (kb + row) * 64 + ((p ^ (row & 7)) << 3);
            async16(ksrc, &Ks[b][i * 2048 + wave * 512]);
            const bf16* vsrc = vp + row * T_SEQ + kb + ((p ^ (row & 7)) << 3);
            async16(vsrc, &Vs[b][i * 2048 + wave * 512]);
        }
    };

    f32x4 acc[4] = {};
    float lsum = 0.0f;

    const int C = qt + 1;
    stage(0, 0);
    for (int c = 0; c < C; c++) {
        __syncthreads();
        if (c + 1 < C) stage((c + 1) * 64, (c + 1) & 1);
        const bf16* ksb = &Ks[c & 1][0];
        const bf16* vsb = &Vs[c & 1][0];
        const bool dg = (c == qt);
        const int na = dg ? (wave + 1) : 4;

        f32x4 sc[4];
        for (int n = 0; n < 4; n++) {
            if (n < na) {
                const bf16* kbase = ksb + (n * 16 + l15) * 64;
                bf16x8 kf0 = *(const bf16x8*)(kbase + sx);
                bf16x8 kf1 = *(const bf16x8*)(kbase + (sx ^ 32));
                f32x4 z = {};
                z = __builtin_amdgcn_mfma_f32_16x16x32_bf16(kf0, qf0, z, 0, 0, 0);
                z = __builtin_amdgcn_mfma_f32_16x16x32_bf16(kf1, qf1, z, 0, 0, 0);
                sc[n] = z;
            }
        }
        for (int n = 0; n < 4; n++) {
            bf16x4 pv;
            if (n < na) {
                const bool dmask = dg && (n == na - 1);
                for (int r = 0; r < 4; r++) {
                    float v = sc[n][r];
                    if (dmask && (quad * 4 + r > l15)) v = -100000.0f;
                    float e = __builtin_amdgcn_exp2f(v);
                    lsum += e;
                    pv[r] = (bf16)e;
                }
            } else {
                pv[0] = pv[1] = pv[2] = pv[3] = (bf16)0.0f;
            }
            *(bf16x4*)(pw + l15 * PST + n * 16 + quad * 4) = pv;
        }
        __builtin_amdgcn_s_waitcnt(0xC07F);
        for (int g = 0; g < 2; g++) {
            bf16x8 pf = *(const bf16x8*)(pw + l15 * PST + g * 32 + quad * 8);
            for (int j = 0; j < 4; j++) {
                const bf16* vbase = vsb + (j * 16 + l15) * 64;
                bf16x8 vf = *(const bf16x8*)(vbase + (g ? (sx ^ 32) : sx));
                acc[j] = __builtin_amdgcn_mfma_f32_16x16x32_bf16(pf, vf, acc[j], 0, 0, 0);
            }
        }
    }

    lsum += __shfl_xor(lsum, 16);
    lsum += __shfl_xor(lsum, 32);
    float linv = 1.0f / lsum;

    bf16* aop = AO + (b_ * T_SEQ + t0w) * 1024 + h_ * 64;
    for (int r = 0; r < 4; r++) {
        float lr = __shfl(linv, quad * 4 + r, 16);
        for (int j = 0; j < 4; j++)
            aop[(quad * 4 + r) * 1024 + j * 16 + l15] = (bf16)(acc[j][r] * lr);
    }
}

// ---------------- GEMM 2: out = AO @ out_w + out_b (fp32 out) ----------------
// 64x128 tile -> 512 blocks (2/CU). Swapped orientation -> float4 stores.
__global__ __launch_bounds__(256) void gemm_out_k(
    const bf16* __restrict__ A, const bf16* __restrict__ Bt,
    const float* __restrict__ bias, float* __restrict__ out) {
    __shared__ __align__(16) bf16 As[64 * 32];
    __shared__ __align__(16) bf16 Bs[128 * 32];
    const int t = threadIdx.x;
    const int lane = t & 63, wave = t >> 6;
    const int l15 = lane & 15, quad = lane >> 4;
    const int wm = wave & 1, wn = wave >> 1;
    const int m0 = blockIdx.y * 64, n0 = blockIdx.x * 128;

    f32x4 acc[4][2] = {};  // acc[j][i]: C^T (row=feature, col=t)

    const bf16* ag = A + (m0 + (t >> 2)) * 1024 + (t & 3) * 8;
    const bf16* bg = Bt + (n0 + (t >> 2)) * 1024 + (t & 3) * 8;
    bf16* as0 = As + wave * 512;
    bf16* bs0 = Bs + wave * 512;
    bf16* bs1 = Bs + 2048 + wave * 512;

    for (int k0 = 0; k0 < 1024; k0 += 32) {
        async16(ag + k0, as0);
        async16(bg + k0, bs0);
        async16(bg + 64 * 1024 + k0, bs1);
        __syncthreads();
        bf16x8 af[2], bfr[4];
        for (int i = 0; i < 2; i++)
            af[i] = *(const bf16x8*)(As + (wm * 32 + i * 16 + l15) * 32 + quad * 8);
        for (int j = 0; j < 4; j++)
            bfr[j] = *(const bf16x8*)(Bs + (wn * 64 + j * 16 + l15) * 32 + quad * 8);
        for (int j = 0; j < 4; j++)
            for (int i = 0; i < 2; i++)
                acc[j][i] = __builtin_amdgcn_mfma_f32_16x16x32_bf16(bfr[j], af[i], acc[j][i], 0, 0, 0);
        __syncthreads();
    }

    for (int j = 0; j < 4; j++) {
        int col0 = n0 + wn * 64 + j * 16 + quad * 4;
        float4 bv = *(const float4*)(bias + col0);
        for (int i = 0; i < 2; i++) {
            int row = m0 + wm * 32 + i * 16 + l15;
            float4 o;
            o.x = acc[j][i][0] + bv.x;
            o.y = acc[j][i][1] + bv.y;
            o.z = acc[j][i][2] + bv.z;
            o.w = acc[j][i][3] + bv.w;
            *(float4*)(out + row * 1024 + col0) = o;
        }
    }
}

// ---------------- launch ----------------
extern "C" void kernel_launch(void* const* d_in, const int* in_sizes, int n_in,
                              void* d_out, int out_size, void* d_ws, size_t ws_size,
                              hipStream_t stream) {
    const float* x     = (const float*)d_in[0];
    const float* qkv_w = (const float*)d_in[1];
    const float* qkv_b = (const float*)d_in[2];
    const float* out_w = (const float*)d_in[3];
    const float* out_b = (const float*)d_in[4];
    float* out = (float*)d_out;

    char* ws = (char*)d_ws;
    bf16* xb   = (bf16*)(ws);                     // 8 MB
    bf16* wbT  = (bf16*)(ws + (8ull << 20));      // 6 MB
    bf16* owbT = (bf16*)(ws + (14ull << 20));     // 2 MB
    bf16* Qb   = (bf16*)(ws + (16ull << 20));     // 8 MB (B,H,T,Dh), pre-scaled
    bf16* Kb   = (bf16*)(ws + (24ull << 20));     // 8 MB (B,H,T,Dh)
    bf16* Vt   = (bf16*)(ws + (32ull << 20));     // 8 MB (B,H,Dh,T)
    bf16* AO   = (bf16*)(ws + (40ull << 20));     // 8 MB (B,T,C)

    prep<<<8192, 256, 0, stream>>>(x, xb, qkv_w, wbT, out_w, owbT);
    gemm_qkv<<<dim3(24, 32), 256, 0, stream>>>(xb, wbT, qkv_b, Qb, Kb, Vt);
    attn<<<1024, 256, 0, stream>>>(Qb, Kb, Vt, AO);
    gemm_out_k<<<dim3(8, 64), 256, 0, stream>>>(AO, owbT, out_b, out);
}